// Round 2
// baseline (400.954 us; speedup 1.0000x reference)
//
#include <hip/hip_runtime.h>

// Fused denorm + ReLU + AdaptiveAvgPool2d(56) for patch groups S=24,32,48.
// Since S < 56, each output pixel averages a <=2x2 input window. Branchless
// form: out = 0.25*(v[rA][cA] + v[rA][cB] + v[rB][cA] + v[rB][cB]) where
// rB==rA (duplicate read) when the row window is 1 wide -- exact average.
//   rA = (i*S)/56,  rB = ((i+1)*S - 1)/56   (= ceil((i+1)S/56) - 1)
//
// Two adjacent channels per block, interleaved in LDS as float2: the four
// gather addresses are identical for both channels, so one ds_read_b64
// serves two maps (halves LDS gather instrs + address VALU vs 1-map/block).

#define C_CH 256
#define OUTS 56
#define NPER 32

template<int S>
__device__ __forceinline__ void group_body(const float* __restrict__ x,
                                           const float* __restrict__ smean,
                                           const float* __restrict__ sstd,
                                           float* __restrict__ out,
                                           int local_bid, int n_base,
                                           float2* __restrict__ lds2) {
    const int n_local = local_bid >> 7;   // 128 channel-pairs per patch
    const int pair    = local_bid & 127;
    const int ch      = pair * 2;
    const int n_glob  = n_base + n_local;

    const float2 mn = *(const float2*)(smean + n_glob * C_CH + ch);
    const float2 sd = *(const float2*)(sstd  + n_glob * C_CH + ch);

    const float* xa = x + (size_t)(n_local * C_CH + ch) * (S * S);
    const float4* a4 = (const float4*)xa;
    const float4* b4 = (const float4*)(xa + S * S);
    float4* l4 = (float4*)lds2;

    const int tid = threadIdx.x;

    // Stage both maps, denorm+ReLU applied, channel-interleaved:
    // lds2[pix] = { chA[pix], chB[pix] }
    constexpr int NV = (S * S) / 4;
    for (int idx = tid; idx < NV; idx += 256) {
        float4 va = a4[idx];
        float4 vb = b4[idx];
        va.x = fmaxf(fmaf(va.x, sd.x, mn.x), 0.0f);
        va.y = fmaxf(fmaf(va.y, sd.x, mn.x), 0.0f);
        va.z = fmaxf(fmaf(va.z, sd.x, mn.x), 0.0f);
        va.w = fmaxf(fmaf(va.w, sd.x, mn.x), 0.0f);
        vb.x = fmaxf(fmaf(vb.x, sd.y, mn.y), 0.0f);
        vb.y = fmaxf(fmaf(vb.y, sd.y, mn.y), 0.0f);
        vb.z = fmaxf(fmaf(vb.z, sd.y, mn.y), 0.0f);
        vb.w = fmaxf(fmaf(vb.w, sd.y, mn.y), 0.0f);
        float4 lo; lo.x = va.x; lo.y = vb.x; lo.z = va.y; lo.w = vb.y;
        float4 hi; hi.x = va.z; hi.y = vb.z; hi.z = va.w; hi.w = vb.w;
        l4[2 * idx]     = lo;
        l4[2 * idx + 1] = hi;
    }
    __syncthreads();

    float* outA = out + (size_t)(n_glob * C_CH + ch) * (OUTS * OUTS);
    float4* oa4 = (float4*)outA;
    float4* ob4 = (float4*)(outA + OUTS * OUTS);

    constexpr int NQ = (OUTS * OUTS) / 4;   // 784 float4 per map
    for (int q = tid; q < NQ; q += 256) {
        const int i  = q / (OUTS / 4);          // const divisor 14
        const int j0 = (q - i * (OUTS / 4)) * 4;
        const int rA = (i * S) / OUTS;
        const int rB = ((i + 1) * S - 1) / OUTS;
        const float2* rowA = lds2 + rA * S;
        const float2* rowB = lds2 + rB * S;

        float oA[4], oB[4];
        #pragma unroll
        for (int k = 0; k < 4; ++k) {
            const int j  = j0 + k;
            const int cA = (j * S) / OUTS;
            const int cB = ((j + 1) * S - 1) / OUTS;
            const float2 v0 = rowA[cA];
            const float2 v1 = rowA[cB];
            const float2 v2 = rowB[cA];
            const float2 v3 = rowB[cB];
            oA[k] = 0.25f * ((v0.x + v1.x) + (v2.x + v3.x));
            oB[k] = 0.25f * ((v0.y + v1.y) + (v2.y + v3.y));
        }
        float4 sa; sa.x = oA[0]; sa.y = oA[1]; sa.z = oA[2]; sa.w = oA[3];
        float4 sb; sb.x = oB[0]; sb.y = oB[1]; sb.z = oB[2]; sb.w = oB[3];
        oa4[q] = sa;
        ob4[q] = sb;
    }
}

__global__ __launch_bounds__(256) void PPIN_DC_20753281974843_kernel(
        const float* __restrict__ p24, const float* __restrict__ p32,
        const float* __restrict__ p48, const float* __restrict__ smean,
        const float* __restrict__ sstd, float* __restrict__ out) {
    __shared__ float2 lds2[48 * 48];   // 18432 B -> 8 blocks/CU (wave-limited)
    const int bid   = blockIdx.x;
    const int group = bid >> 12;       // 4096 blocks per group (32 n * 128 pairs)
    const int local = bid & 4095;
    if (group == 0)      group_body<24>(p24, smean, sstd, out, local, 0,        lds2);
    else if (group == 1) group_body<32>(p32, smean, sstd, out, local, NPER,     lds2);
    else                 group_body<48>(p48, smean, sstd, out, local, 2 * NPER, lds2);
}

extern "C" void kernel_launch(void* const* d_in, const int* in_sizes, int n_in,
                              void* d_out, int out_size, void* d_ws, size_t ws_size,
                              hipStream_t stream) {
    const float* p24   = (const float*)d_in[0];
    const float* p32   = (const float*)d_in[1];
    const float* p48   = (const float*)d_in[2];
    const float* smean = (const float*)d_in[3];
    const float* sstd  = (const float*)d_in[4];
    float* out = (float*)d_out;

    // 3 groups * 32 patches * 128 channel-pairs = 12288 blocks.
    PPIN_DC_20753281974843_kernel<<<dim3(12288), dim3(256), 0, stream>>>(
        p24, p32, p48, smean, sstd, out);
}